// Round 13
// baseline (422.402 us; speedup 1.0000x reference)
//
#include <hip/hip_runtime.h>
#include <hip/hip_bf16.h>

#define NN 50000
#define EE 600000
#define DD 128
#define RR 7
#define SS 8            // R + self-loop slot
#define GG 32
#define NSEG (NN * RR)  // 350000 CSR segments
#define NB1 ((NSEG + 1023) / 1024)   // 342 scan blocks

typedef float f32x4 __attribute__((ext_vector_type(4)));
typedef float f32x2 __attribute__((ext_vector_type(2)));
typedef short short8 __attribute__((ext_vector_type(8)));
typedef unsigned short u16x8 __attribute__((ext_vector_type(8)));

static __device__ __forceinline__ unsigned short f2bf(float f) {
    union { float f; unsigned u; } v; v.f = f;
    unsigned r = v.u + 0x7fff + ((v.u >> 16) & 1);
    return (unsigned short)(r >> 16);
}
static __device__ __forceinline__ float bf2f(unsigned short u) {
    union { unsigned u; float f; } v; v.u = ((unsigned)u) << 16;
    return v.f;
}

// ---- weights prep: Wt2[j=(slot,dout)][k=din] bf16; bias = lin_b + sl_b ----
__global__ void prep_w2(const float* __restrict__ lin_w, const float* __restrict__ sl_w,
                        const float* __restrict__ lin_b, const float* __restrict__ sl_b,
                        unsigned short* __restrict__ Wt2, float* __restrict__ bias) {
    int idx = blockIdx.x * 256 + threadIdx.x;   // 131072
    if (idx < DD) bias[idx] = lin_b[idx] + sl_b[idx];
    if (idx >= 1024 * DD) return;
    int j = idx >> 7;                  // output col: slot*128 + dout
    int k = idx & 127;                 // din
    int slot = j >> 7, dout = j & 127;
    float w = (slot < 7) ? lin_w[(slot * DD + k) * DD + dout] : sl_w[k * DD + dout];
    Wt2[(size_t)j * DD + k] = f2bf(w);
}

// ---------------- CSR build ----------------
__global__ void zero_ints(int* __restrict__ p, int n) {
    int i = blockIdx.x * 256 + threadIdx.x;
    if (i < n) p[i] = 0;
}

__global__ void hist(const int* __restrict__ node_out, const int* __restrict__ rel,
                     int* __restrict__ counts) {
    int e = blockIdx.x * 256 + threadIdx.x;
    if (e >= EE) return;
    atomicAdd(&counts[node_out[e] * RR + rel[e]], 1);
}

__global__ __launch_bounds__(256) void scan1(const int* __restrict__ counts,
                                             int* __restrict__ start, int* __restrict__ bsum) {
    __shared__ int s[256];
    int tid = threadIdx.x;
    int base = blockIdx.x * 1024 + tid * 4;
    int v[4], sum = 0;
    #pragma unroll
    for (int j = 0; j < 4; ++j) {
        v[j] = (base + j < NSEG) ? counts[base + j] : 0;
        sum += v[j];
    }
    s[tid] = sum; __syncthreads();
    for (int off = 1; off < 256; off <<= 1) {
        int t = (tid >= off) ? s[tid - off] : 0;
        __syncthreads();
        s[tid] += t;
        __syncthreads();
    }
    int run = s[tid] - sum;
    if (tid == 255) bsum[blockIdx.x] = s[255];
    #pragma unroll
    for (int j = 0; j < 4; ++j) {
        if (base + j < NSEG) { start[base + j] = run; run += v[j]; }
    }
}

__global__ __launch_bounds__(512) void scan2(int* __restrict__ bsum) {
    __shared__ int s[512];
    int tid = threadIdx.x;
    int v = (tid < NB1) ? bsum[tid] : 0;
    s[tid] = v; __syncthreads();
    for (int off = 1; off < 512; off <<= 1) {
        int t = (tid >= off) ? s[tid - off] : 0;
        __syncthreads();
        s[tid] += t;
        __syncthreads();
    }
    if (tid < NB1) bsum[tid] = s[tid] - v;
}

__global__ void scan3(const int* __restrict__ start, const int* __restrict__ bsum,
                      const int* __restrict__ counts, int2* __restrict__ segd) {
    int i = blockIdx.x * 256 + threadIdx.x;
    if (i < NSEG) segd[i] = make_int2(start[i] + bsum[i >> 10], counts[i]);
}

// record: x = (rel << 16) | node_in, y = weight bits
__global__ void fill(const int* __restrict__ node_in, const int* __restrict__ node_out,
                     const int* __restrict__ rel, const float* __restrict__ ew,
                     const int2* __restrict__ segd, int* __restrict__ cursor,
                     int2* __restrict__ edges) {
    int e = blockIdx.x * 256 + threadIdx.x;
    if (e >= EE) return;
    int seg = node_out[e] * RR + rel[e];
    int pos = segd[seg].x + atomicAdd(&cursor[seg], 1);
    edges[pos] = make_int2((rel[e] << 16) | node_in[e], __float_as_int(ew[e]));
}

// layer-0 bf16 shadow of x.  EXACTLY NN*32 threads (6250 blocks).
__global__ void init_hb(const float* __restrict__ x, unsigned short* __restrict__ hb) {
    int t = blockIdx.x * 256 + threadIdx.x;     // [0, NN*32)
    if (t >= NN * 32) return;
    f32x4 v = ((const f32x4*)x)[t];
    unsigned long long pack = (unsigned long long)f2bf(v.x)
                            | ((unsigned long long)f2bf(v.y) << 16)
                            | ((unsigned long long)f2bf(v.z) << 32)
                            | ((unsigned long long)f2bf(v.w) << 48);
    ((unsigned long long*)hb)[t] = pack;
}

// ---- dense GEMM v3: P[n][1024] = hb[n][128] @ Wcat; A in registers, no LDS ----
// grid = ceil(N/128) * 4; block = (row panel, 2 col-blocks of 128).
__global__ __launch_bounds__(256) void gemm_p(
        const unsigned short* __restrict__ hb,   // [N][128] bf16
        const unsigned short* __restrict__ Wt2,  // [1024][128] bf16
        unsigned short* __restrict__ P) {        // [N][1024] bf16
    int tid = threadIdx.x;
    int wid = tid >> 6, lane = tid & 63;
    int wr = wid >> 1, wc = wid & 1;
    int lm = lane & 15, lg = lane >> 4;
    int bm0 = (blockIdx.x >> 2) * 128;
    int cb0 = (blockIdx.x & 3) * 2;

    // A fragments: rows wr*64 + mi*16 + lm, k = ks*32 + lg*8
    short8 af[4][4];
    #pragma unroll
    for (int mi = 0; mi < 4; ++mi) {
        int gr = bm0 + wr * 64 + mi * 16 + lm;
        #pragma unroll
        for (int ks = 0; ks < 4; ++ks) {
            short8 t = {};
            if (gr < NN) t = *(const short8*)(hb + (size_t)gr * DD + ks * 32 + lg * 8);
            af[mi][ks] = t;
        }
    }
    #pragma unroll
    for (int cc = 0; cc < 2; ++cc) {
        int cb = cb0 + cc;
        f32x4 acc[4][4] = {};
        #pragma unroll
        for (int ks = 0; ks < 4; ++ks) {
            short8 bfr[4];
            #pragma unroll
            for (int ni = 0; ni < 4; ++ni)
                bfr[ni] = *(const short8*)(Wt2 + (size_t)(cb * 128 + wc * 64 + ni * 16 + lm) * DD
                                           + ks * 32 + lg * 8);
            #pragma unroll
            for (int mi = 0; mi < 4; ++mi)
                #pragma unroll
                for (int ni = 0; ni < 4; ++ni)
                    acc[mi][ni] = __builtin_amdgcn_mfma_f32_16x16x32_bf16(af[mi][ks], bfr[ni], acc[mi][ni], 0, 0, 0);
        }
        #pragma unroll
        for (int mi = 0; mi < 4; ++mi) {
            #pragma unroll
            for (int v = 0; v < 4; ++v) {
                int gm = bm0 + wr * 64 + mi * 16 + lg * 4 + v;
                if (gm >= NN) continue;
                #pragma unroll
                for (int ni = 0; ni < 4; ++ni) {
                    int j = cb * 128 + wc * 64 + ni * 16 + lm;
                    P[(size_t)gm * 1024 + j] = f2bf(acc[mi][ni][v]);
                }
            }
        }
    }
}

// ---- gather in P-space: wave/node, records depth-5 + hv depth-4 pipeline ----
#define PROW(r) (const unsigned*)(P + (size_t)((((r).x & 0xFFFF) << 3) | ((r).x >> 16)) * DD + lane * 2)
__global__ __launch_bounds__(256) void gather_p(
        const unsigned short* __restrict__ P,    // [N][8][128] bf16
        const int2* __restrict__ segd,
        const int2* __restrict__ edges,          // +8 zeroed slop records
        const float* __restrict__ bias,
        const float* __restrict__ hprev,         // fp32 [N][128]
        float* __restrict__ hout,
        unsigned short* __restrict__ hb_next,
        int write_next) {
    int tid = threadIdx.x;
    int wv = tid >> 6, lane = tid & 63;
    int node = blockIdx.x * 4 + wv;              // 12500*4 = 50000 exact
    int st = segd[node * RR].x;
    int2 s6 = segd[node * RR + 6];
    int end = s6.x + s6.y;

    float ax = 0.f, ay = 0.f;
    int2 r0 = edges[st];
    int2 r1 = edges[st + 1];
    int2 r2 = edges[st + 2];
    int2 r3 = edges[st + 3];
    int2 r4 = edges[st + 4];
    unsigned hv0 = *PROW(r0);
    unsigned hv1 = *PROW(r1);
    unsigned hv2 = *PROW(r2);
    unsigned hv3 = *PROW(r3);
    for (int i = st; i < end; ++i) {
        int2 r5 = edges[i + 5];
        unsigned hv4 = *PROW(r4);
        float w = __int_as_float(r0.y);
        ax += bf2f((unsigned short)(hv0 & 0xFFFF)) * w;
        ay += bf2f((unsigned short)(hv0 >> 16)) * w;
        r0 = r1; r1 = r2; r2 = r3; r3 = r4; r4 = r5;
        hv0 = hv1; hv1 = hv2; hv2 = hv3; hv3 = hv4;
    }
    unsigned hs = *(const unsigned*)(P + ((size_t)node * 8 + 7) * DD + lane * 2);
    float bx = bias[lane * 2], by = bias[lane * 2 + 1];
    f32x2 hp = ((const f32x2*)hprev)[(size_t)node * 64 + lane];
    float vx = fmaxf(ax + bf2f((unsigned short)(hs & 0xFFFF)) + bx, 0.f) + hp.x;
    float vy = fmaxf(ay + bf2f((unsigned short)(hs >> 16)) + by, 0.f) + hp.y;
    ((f32x2*)hout)[(size_t)node * 64 + lane] = (f32x2){vx, vy};
    if (write_next)
        ((unsigned*)hb_next)[(size_t)node * 64 + lane] =
            (unsigned)f2bf(vx) | ((unsigned)f2bf(vy) << 16);
}

__global__ void zero_gf(float* gf) {
    int t = blockIdx.x * 256 + threadIdx.x;
    if (t < GG * DD) gf[t] = 0.f;
}

// Parallel readout: block = 128 nodes, 8 row-streams x 32 lanes (f32x4 cols).
__global__ __launch_bounds__(256) void readout(const float* __restrict__ h,
                                               const int* __restrict__ n2g,
                                               float* __restrict__ gf) {
    int c0 = blockIdx.x * 128;
    int rg = threadIdx.x >> 5, d4 = threadIdx.x & 31;
    f32x4 acc = {0.f, 0.f, 0.f, 0.f};
    int cur = -1;
    #pragma unroll 4
    for (int it = 0; it < 16; ++it) {
        int row = c0 + it * 8 + rg;
        if (row >= NN) break;
        int g = n2g[row];
        if (g != cur) {
            if (cur >= 0) {
                atomicAdd(&gf[cur * DD + d4 * 4 + 0], acc.x);
                atomicAdd(&gf[cur * DD + d4 * 4 + 1], acc.y);
                atomicAdd(&gf[cur * DD + d4 * 4 + 2], acc.z);
                atomicAdd(&gf[cur * DD + d4 * 4 + 3], acc.w);
            }
            cur = g;
            acc = (f32x4){0.f, 0.f, 0.f, 0.f};
        }
        acc += ((const f32x4*)h)[(size_t)row * 32 + d4];
    }
    if (cur >= 0) {
        atomicAdd(&gf[cur * DD + d4 * 4 + 0], acc.x);
        atomicAdd(&gf[cur * DD + d4 * 4 + 1], acc.y);
        atomicAdd(&gf[cur * DD + d4 * 4 + 2], acc.z);
        atomicAdd(&gf[cur * DD + d4 * 4 + 3], acc.w);
    }
}

extern "C" void kernel_launch(void* const* d_in, const int* in_sizes, int n_in,
                              void* d_out, int out_size, void* d_ws, size_t ws_size,
                              hipStream_t stream) {
    const float* x      = (const float*)d_in[0];
    const int* node_in  = (const int*)d_in[1];
    const int* node_out = (const int*)d_in[2];
    const int* relation = (const int*)d_in[3];
    const float* ew     = (const float*)d_in[4];
    const int* n2g      = (const int*)d_in[5];
    const float* sl_w[3]  = {(const float*)d_in[8],  (const float*)d_in[12], (const float*)d_in[16]};
    const float* sl_b[3]  = {(const float*)d_in[9],  (const float*)d_in[13], (const float*)d_in[17]};
    const float* lin_w[3] = {(const float*)d_in[10], (const float*)d_in[14], (const float*)d_in[18]};
    const float* lin_b[3] = {(const float*)d_in[11], (const float*)d_in[15], (const float*)d_in[19]};

    float* out = (float*)d_out;
    float* gf = out;                       // [G,D]
    float* nf = out + GG * DD;             // [N,D]

    char* ws = (char*)d_ws;
    size_t off = 0;
    unsigned short* P  = (unsigned short*)(ws + off); off += (size_t)NN * 1024 * 2;   // 102.4 MB
    unsigned short* hb0 = (unsigned short*)(ws + off); off += (size_t)NN * DD * 2;    // 12.8 MB
    unsigned short* hb1 = (unsigned short*)(ws + off); off += (size_t)NN * DD * 2;    // 12.8 MB
    float* hA   = (float*)(ws + off);            off += (size_t)NN * DD * 4;          // 25.6 MB
    unsigned short* Wt2 = (unsigned short*)(ws + off); off += (size_t)3 * 1024 * DD * 2;
    float* bias = (float*)(ws + off);            off += 3 * DD * 4;
    int* counts = (int*)(ws + off);              off += (size_t)NSEG * 4;
    int* cursor = (int*)(ws + off);              off += (size_t)NSEG * 4;
    int* start  = (int*)(ws + off);              off += (size_t)NSEG * 4;
    int2* segd  = (int2*)(ws + off);             off += (size_t)NSEG * 8;
    int* bsum   = (int*)(ws + off);              off += 512 * 4;
    int2* edges = (int2*)(ws + off);             off += (size_t)(EE + 8) * 8;         // +slop

    for (int l = 0; l < 3; ++l)
        prep_w2<<<512, 256, 0, stream>>>(lin_w[l], sl_w[l], lin_b[l], sl_b[l],
                                         Wt2 + (size_t)l * 1024 * DD, bias + l * DD);

    // CSR build (layer-invariant)
    zero_ints<<<(2 * NSEG + 255) / 256, 256, 0, stream>>>(counts, 2 * NSEG);
    zero_ints<<<1, 64, 0, stream>>>((int*)(edges + EE), 16);   // zero slop records
    hist<<<(EE + 255) / 256, 256, 0, stream>>>(node_out, relation, counts);
    scan1<<<NB1, 256, 0, stream>>>(counts, start, bsum);
    scan2<<<1, 512, 0, stream>>>(bsum);
    scan3<<<(NSEG + 255) / 256, 256, 0, stream>>>(start, bsum, counts, segd);
    fill<<<(EE + 255) / 256, 256, 0, stream>>>(node_in, node_out, relation, ew,
                                               segd, cursor, edges);
    init_hb<<<(NN * 32) / 256, 256, 0, stream>>>(x, hb0);      // 6250 blocks exact

    const float* hcur = x;
    float* houts[3] = { nf, hA, nf };
    unsigned short* hbs[2] = { hb0, hb1 };
    for (int l = 0; l < 3; ++l) {
        gemm_p<<<((NN + 127) / 128) * 4, 256, 0, stream>>>(
            hbs[l & 1], Wt2 + (size_t)l * 1024 * DD, P);
        gather_p<<<NN / 4, 256, 0, stream>>>(
            P, segd, edges, bias + l * DD, hcur, houts[l],
            hbs[(l + 1) & 1], l < 2 ? 1 : 0);
        hcur = houts[l];
    }
    zero_gf<<<(GG * DD + 255) / 256, 256, 0, stream>>>(gf);
    readout<<<(NN + 127) / 128, 256, 0, stream>>>(nf, n2g, gf);
}